// Round 3
// baseline (35.749 us; speedup 1.0000x reference)
//
#include <hip/hip_runtime.h>

// LIF spiking-neuron forward: x[B=64, T=100, N=4096] fp32, thresh[N] fp32.
// Sequential scan over T per (b,n) chain; B*N chains independent.
// mem = mem*0.5 + x_t; spk = (mem - th >= 0); mem = spk ? 0 : mem.
// TAU=0.5 => mul exact => bitwise-identical to numpy reference.
//
// R2: scalar float/thread -> 262144 threads = 4 waves/SIMD (2x TLP vs R1).
// R1 post-mortem: compiler collapsed the float2 double-buffer (VGPR=32 < the
// 40 needed for live bufs), occupancy stayed 2 waves/SIMD, dur unchanged.
// Latency hiding now rides on TLP; depth-10 scalar double-buffer kept as ILP.

constexpr int T = 100;
constexpr int N = 4096;
constexpr int B = 64;
constexpr int U = 10;        // prefetch group size
constexpr int NG = T / U;    // 10 groups (even -> g += 2 pairing is safe)

__global__ __launch_bounds__(256) void lif_fwd(const float* __restrict__ x,
                                               const float* __restrict__ thresh,
                                               float* __restrict__ out) {
    const int idx = blockIdx.x * 256 + threadIdx.x;   // [0, B*N)
    const int n   = idx & (N - 1);
    const int b   = idx >> 12;

    const float th = thresh[n];
    float mem = 0.f;

    const long row = (long)b * T * N + n;
    const float* __restrict__ xp = x + row;
    float* __restrict__ op = out + row;

    float bufA[U], bufB[U];

    // prologue: group 0 -> bufA
    #pragma unroll
    for (int u = 0; u < U; ++u) bufA[u] = xp[(long)u * N];

    for (int g = 0; g < NG; g += 2) {
        // prefetch group g+1 -> bufB
        #pragma unroll
        for (int u = 0; u < U; ++u) bufB[u] = xp[(long)((g + 1) * U + u) * N];

        // compute + store group g from bufA
        #pragma unroll
        for (int u = 0; u < U; ++u) {
            const float m = mem * 0.5f + bufA[u];
            const bool s = (m - th) >= 0.0f;
            op[(long)(g * U + u) * N] = s ? 1.0f : 0.0f;
            mem = s ? 0.0f : m;
        }

        // prefetch group g+2 -> bufA
        if (g + 2 < NG) {
            #pragma unroll
            for (int u = 0; u < U; ++u) bufA[u] = xp[(long)((g + 2) * U + u) * N];
        }

        // compute + store group g+1 from bufB
        #pragma unroll
        for (int u = 0; u < U; ++u) {
            const float m = mem * 0.5f + bufB[u];
            const bool s = (m - th) >= 0.0f;
            op[(long)((g + 1) * U + u) * N] = s ? 1.0f : 0.0f;
            mem = s ? 0.0f : m;
        }
    }
}

extern "C" void kernel_launch(void* const* d_in, const int* in_sizes, int n_in,
                              void* d_out, int out_size, void* d_ws, size_t ws_size,
                              hipStream_t stream) {
    const float* x  = (const float*)d_in[0];
    const float* th = (const float*)d_in[1];
    float* out = (float*)d_out;

    const int total = B * N;              // 262144 threads
    lif_fwd<<<total / 256, 256, 0, stream>>>(x, th, out);
}